// Round 6
// baseline (270.494 us; speedup 1.0000x reference)
//
#include <hip/hip_runtime.h>
#include <hip/hip_bf16.h>

typedef __bf16 bf16_t;
typedef __bf16 bf16x8 __attribute__((ext_vector_type(8)));
typedef float f32x4 __attribute__((ext_vector_type(4)));
typedef float f32x2 __attribute__((ext_vector_type(2)));

#define MFMA16(a, b, c) __builtin_amdgcn_mfma_f32_16x16x32_bf16((a), (b), (c), 0, 0, 0)

__device__ __forceinline__ void gl_lds16(const bf16_t* g, bf16_t* l) {
  __builtin_amdgcn_global_load_lds(
      (const __attribute__((address_space(1))) void*)g,
      (__attribute__((address_space(3))) void*)l, 16, 0, 0);
}

__device__ __forceinline__ unsigned pack_bf16(float a, float b) {
  union { bf16_t h[2]; unsigned u; } c;
  c.h[0] = (bf16_t)a; c.h[1] = (bf16_t)b;
  return c.u;
}

// bijective XCD-chunked swizzle for flattened block index (nwg % 8 == 0)
__device__ __forceinline__ int xcd_swz(int orig, int nwg) {
  return (orig & 7) * (nwg >> 3) + (orig >> 3);
}

// B=4, T=2048, D=512, H=8, DH=64 — hardcoded
// ---------------------------------------------------------------------------
__global__ __launch_bounds__(256) void k_cvt_bf16(const float* __restrict__ in,
                                                  bf16_t* __restrict__ out, int n4) {
  int i = blockIdx.x * 256 + threadIdx.x;
  if (i >= n4) return;
  float4 f = ((const float4*)in)[i];
  union { bf16_t h[4]; uint2 u; } cv;
  cv.h[0] = (bf16_t)f.x; cv.h[1] = (bf16_t)f.y; cv.h[2] = (bf16_t)f.z; cv.h[3] = (bf16_t)f.w;
  ((uint2*)out)[i] = cv.u;
}

__global__ __launch_bounds__(256) void k_transpose_bf16(const float* __restrict__ W,
                                                        bf16_t* __restrict__ WT,
                                                        int K, int N) {
  __shared__ float tile[64][65];
  int bk = blockIdx.x * 64, bn = blockIdx.y * 64;
  int tx = threadIdx.x & 63, ty = threadIdx.x >> 6;
  for (int i = ty; i < 64; i += 4)
    tile[i][tx] = W[(size_t)(bk + i) * N + bn + tx];
  __syncthreads();
  for (int i = ty; i < 64; i += 4)
    WT[(size_t)(bn + i) * K + bk + tx] = (bf16_t)tile[tx][i];
}

// ---------------------------------------------------------------------------
// C[M][N] = A[M][K] @ Bt[N][K]^T, bf16 in, fp32 accum. 2-phase double-buffered
// global_load_lds staging; XCD-chunked block swizzle.
template <int MODE, int BM>
__global__ __launch_bounds__(256) void k_gemm_bt(
    const bf16_t* __restrict__ A, const bf16_t* __restrict__ Bt,
    float* __restrict__ Cf, bf16_t* __restrict__ Cb,
    bf16_t* __restrict__ Cb2, bf16_t* __restrict__ Cb3,
    int M, int N, int K, const float* __restrict__ coef) {
  __shared__ __align__(16) bf16_t As[2][BM * 32];
  __shared__ __align__(16) bf16_t Bs[2][128 * 32];
  constexpr int NF = (BM == 128) ? 4 : 2;
  int tid = threadIdx.x;
  int lane = tid & 63, wave = tid >> 6;
  int nwg = gridDim.x * gridDim.y;
  int wg = xcd_swz(blockIdx.y * gridDim.x + blockIdx.x, nwg);
  int bm = (wg % gridDim.x) * BM, bn = (wg / gridDim.x) * 128;
  int wr = (BM == 128) ? (wave >> 1) * 64 : 0;
  int wc = (BM == 128) ? (wave & 1) * 64 : wave * 32;
  int lr = lane & 15, lk = (lane >> 4) * 8;
  int srow = tid >> 2, scol = (tid & 3) * 8;

  f32x4 zero = {0.f, 0.f, 0.f, 0.f};
  f32x4 acc[4][NF];
#pragma unroll
  for (int m = 0; m < 4; ++m)
#pragma unroll
    for (int n = 0; n < NF; ++n) acc[m][n] = zero;

  const bf16_t* pA = A + (size_t)(bm + srow) * K + scol;
  const bf16_t* pB = Bt + (size_t)(bn + srow) * K + scol;

  auto STAGE = [&](int buf, int k0) {
    bf16_t* lA = &As[buf][tid * 8];
    bf16_t* lB = &Bs[buf][tid * 8];
    gl_lds16(pA + k0, lA);
    if (BM == 128) gl_lds16(pA + (size_t)64 * K + k0, lA + 2048);
    gl_lds16(pB + k0, lB);
    gl_lds16(pB + (size_t)64 * K + k0, lB + 2048);
  };

  STAGE(0, 0);
  __syncthreads();
  int buf = 0;
  for (int k0 = 0; k0 < K; k0 += 32) {
    if (k0 + 32 < K) STAGE(buf ^ 1, k0 + 32);
    bf16x8 a[4], b[NF];
#pragma unroll
    for (int m = 0; m < 4; ++m) a[m] = *(const bf16x8*)&As[buf][(wr + m * 16 + lr) * 32 + lk];
#pragma unroll
    for (int n = 0; n < NF; ++n) b[n] = *(const bf16x8*)&Bs[buf][(wc + n * 16 + lr) * 32 + lk];
    __builtin_amdgcn_s_setprio(1);
#pragma unroll
    for (int m = 0; m < 4; ++m)
#pragma unroll
      for (int n = 0; n < NF; ++n)
        acc[m][n] = MFMA16(a[m], b[n], acc[m][n]);
    __builtin_amdgcn_s_setprio(0);
    __syncthreads();
    buf ^= 1;
  }

  float c8[8];
  if (MODE == 4) {
#pragma unroll
    for (int i = 0; i < 8; ++i) c8[i] = coef[i];
  }
  int rbase = (lane >> 4) * 4;
#pragma unroll
  for (int m = 0; m < 4; ++m) {
#pragma unroll
    for (int n = 0; n < NF; ++n) {
#pragma unroll
      for (int r = 0; r < 4; ++r) {
        int gm = bm + wr + m * 16 + rbase + r;
        int gn = bn + wc + n * 16 + lr;
        float v = acc[m][n][r];
        if (MODE == 0) {
          Cf[(size_t)gm * N + gn] = v;
        } else if (MODE == 4) {
          float xx = fminf(fmaxf(v, -4.f), 4.f);
          float p = c8[0], pw = 1.f;
#pragma unroll
          for (int i = 1; i < 8; ++i) { pw *= xx; p += c8[i] * pw; }
          Cb[(size_t)gm * N + gn] = (bf16_t)p;
        } else {  // 5: fused QKV scatter
          int mat = gn >> 9, col = gn & 511;
          int b_ = gm >> 11, t_ = gm & 2047, h_ = col >> 6, d_ = col & 63;
          if (mat == 0)
            Cb[(((size_t)b_ * 8 + h_) * 2048 + t_) * 64 + d_] = (bf16_t)v;
          else if (mat == 1)
            Cb2[(((size_t)b_ * 8 + h_) * 2048 + t_) * 64 + d_] = (bf16_t)v;
          else
            Cb3[(((size_t)b_ * 8 + h_) * 64 + d_) * 2048 + t_] = (bf16_t)v;
        }
      }
    }
  }
}

// ---------------------------------------------------------------------------
// Two-pass attention, QBLK=64, KVBLK=64, 4 waves (wave owns 16 q rows).
// Swapped QK^T (S^T = mfma(K,Q)): in-register softmax, packed f32x2 VALU
// (v_pk_fma_f32), P packed straight into bf16 A-fragments; V staged with a
// column-quad permutation so PV aligns. K,V double-buffered in XOR-swizzled
// LDS, reg-staged 2 tiles ahead, ONE barrier per kt.
__global__ __launch_bounds__(256) void k_attn(
    const bf16_t* __restrict__ qb, const bf16_t* __restrict__ kb,
    const bf16_t* __restrict__ vtb, bf16_t* __restrict__ ob,
    const float* __restrict__ exp_c) {
  __shared__ __align__(16) bf16_t Ks[2][64 * 64];
  __shared__ __align__(16) bf16_t Vs[2][64 * 64];
  int tid = threadIdx.x, lane = tid & 63, wave = tid >> 6;
  int b0 = blockIdx.x;
  int bid = (b0 & 7) * 128 + (b0 >> 3);  // XCD-chunked (1024 % 8 == 0)
  int qt = bid & 31, bh = bid >> 5;
  const size_t bho = (size_t)bh * (2048 * 64);
  const bf16_t* Q = qb + bho + (size_t)qt * 64 * 64;
  const bf16_t* Kp = kb + bho;
  const bf16_t* Vp = vtb + bho;  // [64 dh][2048 t]
  int lr = lane & 15, lg = lane >> 4;

  // Q fragments (registers, whole kernel). Q is B-operand: rows = q.
  bf16x8 qa[2];
#pragma unroll
  for (int h = 0; h < 2; ++h)
    qa[h] = *(const bf16x8*)&Q[(wave * 16 + lr) * 64 + h * 32 + lg * 8];

  f32x2 ec2[7];
#pragma unroll
  for (int i = 0; i < 7; ++i) { float e = exp_c[i]; ec2[i] = f32x2{e, e}; }
  const f32x2 c125 = {0.125f, 0.125f};
  const f32x2 eps2 = {1e-8f, 1e-8f};

  // staging geometry: 256 threads, 64 rows x (2 x 16B chunks per row)
  int krow = tid >> 2;
  int c = tid & 3;
  int c0 = c * 16, c1 = c0 + 64;
  int swr = (krow & 7) << 4;
  int ldsW0 = (krow * 128 + c0) ^ swr;
  int ldsW1 = (krow * 128 + c1) ^ swr;
  // V column-quad permutation: claim quad qc = ((qa&3)<<1)|(qa>>2)
  int qc0 = (((2 * c) & 3) << 1) | ((2 * c) >> 2);
  int qc1 = (((2 * c + 1) & 3) << 1) | ((2 * c + 1) >> 2);
  int vw00 = (krow * 128 + qc0 * 8) ^ swr;
  int vw01 = (krow * 128 + qc1 * 8) ^ swr;
  int vw10 = (krow * 128 + 64 + qc0 * 8) ^ swr;
  int vw11 = (krow * 128 + 64 + qc1 * 8) ^ swr;
  const char* gK = (const char*)(Kp + (size_t)krow * 64) + c0;   // + kt*8192 (+64)
  const char* gV = (const char*)(Vp + (size_t)krow * 2048) + c0; // + kt*128 (+64)

  f32x4 zero = {0.f, 0.f, 0.f, 0.f};

  // ================= pass 1: exact row max (S^T layout, packed max) ========
  uint4 ka0 = *(const uint4*)(gK);
  uint4 ka1 = *(const uint4*)(gK + 64);
  *(uint4*)((char*)Ks[0] + ldsW0) = ka0;
  *(uint4*)((char*)Ks[0] + ldsW1) = ka1;
  ka0 = *(const uint4*)(gK + 8192);
  ka1 = *(const uint4*)(gK + 8192 + 64);
  __syncthreads();

  f32x2 rmax2 = {-3.4e38f, -3.4e38f};
  int cur = 0;
  for (int kt = 0; kt < 32; ++kt) {
    const char* kbase = (const char*)Ks[cur];
    __builtin_amdgcn_s_setprio(1);
#pragma unroll
    for (int n = 0; n < 4; ++n) {
      int row = n * 16 + lr, sw = (row & 7) << 4;
      bf16x8 kb0 = *(const bf16x8*)(kbase + ((row * 128 + lg * 16) ^ sw));
      bf16x8 kb1 = *(const bf16x8*)(kbase + ((row * 128 + 64 + lg * 16) ^ sw));
      f32x4 s = MFMA16(kb1, qa[1], MFMA16(kb0, qa[0], zero));
      rmax2 = __builtin_elementwise_max(rmax2, f32x2{s[0], s[1]});
      rmax2 = __builtin_elementwise_max(rmax2, f32x2{s[2], s[3]});
    }
    __builtin_amdgcn_s_setprio(0);
    if (kt < 31) {
      *(uint4*)((char*)Ks[cur ^ 1] + ldsW0) = ka0;
      *(uint4*)((char*)Ks[cur ^ 1] + ldsW1) = ka1;
    }
    if (kt < 30) {
      ka0 = *(const uint4*)(gK + (size_t)(kt + 2) * 8192);
      ka1 = *(const uint4*)(gK + (size_t)(kt + 2) * 8192 + 64);
    }
    __syncthreads();
    cur ^= 1;
  }
  float rmax = fmaxf(rmax2[0], rmax2[1]);
  rmax = fmaxf(rmax, __shfl_xor(rmax, 16));
  rmax = fmaxf(rmax, __shfl_xor(rmax, 32));
  float rm8 = rmax * 0.125f;  // exact (pow2)
  const f32x2 nrm8 = {-rm8, -rm8};

  // ================= pass 2 =================
  f32x4 oacc[4];
#pragma unroll
  for (int n = 0; n < 4; ++n) oacc[n] = zero;
  f32x2 rsum2 = {0.f, 0.f};

  uint4 va0, va1;
  ka0 = *(const uint4*)(gK);
  ka1 = *(const uint4*)(gK + 64);
  va0 = *(const uint4*)(gV);
  va1 = *(const uint4*)(gV + 64);
  *(uint4*)((char*)Ks[0] + ldsW0) = ka0;
  *(uint4*)((char*)Ks[0] + ldsW1) = ka1;
  *(uint2*)((char*)Vs[0] + vw00) = make_uint2(va0.x, va0.y);
  *(uint2*)((char*)Vs[0] + vw01) = make_uint2(va0.z, va0.w);
  *(uint2*)((char*)Vs[0] + vw10) = make_uint2(va1.x, va1.y);
  *(uint2*)((char*)Vs[0] + vw11) = make_uint2(va1.z, va1.w);
  ka0 = *(const uint4*)(gK + 8192);
  ka1 = *(const uint4*)(gK + 8192 + 64);
  va0 = *(const uint4*)(gV + 128);
  va1 = *(const uint4*)(gV + 128 + 64);
  __syncthreads();

  cur = 0;
  for (int kt = 0; kt < 32; ++kt) {
    const char* kbase = (const char*)Ks[cur];
    const char* vbase = (const char*)Vs[cur];
    // ---- QK^T (swapped) + packed poly + pack to bf16 A-fragments
    unsigned pk[4][2];
    __builtin_amdgcn_s_setprio(1);
#pragma unroll
    for (int n = 0; n < 4; ++n) {
      int row = n * 16 + lr, sw = (row & 7) << 4;
      bf16x8 kb0 = *(const bf16x8*)(kbase + ((row * 128 + lg * 16) ^ sw));
      bf16x8 kb1 = *(const bf16x8*)(kbase + ((row * 128 + 64 + lg * 16) ^ sw));
      f32x4 s = MFMA16(kb1, qa[1], MFMA16(kb0, qa[0], zero));
      f32x2 x01 = __builtin_elementwise_fma(f32x2{s[0], s[1]}, c125, nrm8);
      f32x2 x23 = __builtin_elementwise_fma(f32x2{s[2], s[3]}, c125, nrm8);
      f32x2 p01 = ec2[6], p23 = ec2[6];
#pragma unroll
      for (int i = 5; i >= 0; --i) {
        p01 = __builtin_elementwise_fma(p01, x01, ec2[i]);
        p23 = __builtin_elementwise_fma(p23, x23, ec2[i]);
      }
      p01 = __builtin_elementwise_max(p01, eps2);
      p23 = __builtin_elementwise_max(p23, eps2);
      rsum2 += p01;
      rsum2 += p23;
      pk[n][0] = pack_bf16(p01[0], p01[1]);
      pk[n][1] = pack_bf16(p23[0], p23[1]);
    }
    __builtin_amdgcn_s_setprio(0);
    union { unsigned u[4]; bf16x8 v; } pa0, pa1;
    pa0.u[0] = pk[0][0]; pa0.u[1] = pk[0][1]; pa0.u[2] = pk[1][0]; pa0.u[3] = pk[1][1];
    pa1.u[0] = pk[2][0]; pa1.u[1] = pk[2][1]; pa1.u[2] = pk[3][0]; pa1.u[3] = pk[3][1];
    // ---- stage next K/V tile; prefetch tile after that
    if (kt < 31) {
      *(uint4*)((char*)Ks[cur ^ 1] + ldsW0) = ka0;
      *(uint4*)((char*)Ks[cur ^ 1] + ldsW1) = ka1;
      *(uint2*)((char*)Vs[cur ^ 1] + vw00) = make_uint2(va0.x, va0.y);
      *(uint2*)((char*)Vs[cur ^ 1] + vw01) = make_uint2(va0.z, va0.w);
      *(uint2*)((char*)Vs[cur ^ 1] + vw10) = make_uint2(va1.x, va1.y);
      *(uint2*)((char*)Vs[cur ^ 1] + vw11) = make_uint2(va1.z, va1.w);
    }
    if (kt < 30) {
      ka0 = *(const uint4*)(gK + (size_t)(kt + 2) * 8192);
      ka1 = *(const uint4*)(gK + (size_t)(kt + 2) * 8192 + 64);
      va0 = *(const uint4*)(gV + (size_t)(kt + 2) * 128);
      va1 = *(const uint4*)(gV + (size_t)(kt + 2) * 128 + 64);
    }
    // ---- PV: oacc[dd] += P(k-chunk t) x V(perm-staged)
    __builtin_amdgcn_s_setprio(1);
#pragma unroll
    for (int dd = 0; dd < 4; ++dd) {
      int row = dd * 16 + lr, sw = (row & 7) << 4;
      bf16x8 v0 = *(const bf16x8*)(vbase + ((row * 128 + lg * 16) ^ sw));
      bf16x8 v1 = *(const bf16x8*)(vbase + ((row * 128 + 64 + lg * 16) ^ sw));
      oacc[dd] = MFMA16(pa1.v, v1, MFMA16(pa0.v, v0, oacc[dd]));
    }
    __builtin_amdgcn_s_setprio(0);
    __syncthreads();
    cur ^= 1;
  }
  float rsum = rsum2[0] + rsum2[1];
  rsum += __shfl_xor(rsum, 16);
  rsum += __shfl_xor(rsum, 32);
  float rs4[4];
#pragma unroll
  for (int r = 0; r < 4; ++r) rs4[r] = __shfl(rsum, lg * 4 + r);

  int b_ = bh >> 3, h_ = bh & 7;
#pragma unroll
  for (int dd = 0; dd < 4; ++dd)
#pragma unroll
    for (int r = 0; r < 4; ++r) {
      int t_ = qt * 64 + wave * 16 + lg * 4 + r;
      int d_ = dd * 16 + lr;
      float val = oacc[dd][r] / rs4[r];
      ob[(((size_t)b_ * 2048 + t_) * 8 + h_) * 64 + d_] = (bf16_t)val;
    }
}

// ---------------------------------------------------------------------------
// Fused residual + LayerNorm (replicates Newton rsqrt exactly: 3 iters from 0.5).
__global__ __launch_bounds__(256) void k_ln(
    const float* __restrict__ xa, const float* __restrict__ xb,
    const float* __restrict__ gamma, const float* __restrict__ beta,
    float* __restrict__ outf, bf16_t* __restrict__ outb) {
  int row = blockIdx.x * 4 + (threadIdx.x >> 6);
  int lane = threadIdx.x & 63;
  const float* pa = xa + (size_t)row * 512;
  const float* pb = xb + (size_t)row * 512;
  float4 a0 = ((const float4*)pa)[lane];
  float4 a1 = ((const float4*)pa)[lane + 64];
  float4 b0 = ((const float4*)pb)[lane];
  float4 b1 = ((const float4*)pb)[lane + 64];
  float x[8] = {a0.x + b0.x, a0.y + b0.y, a0.z + b0.z, a0.w + b0.w,
                a1.x + b1.x, a1.y + b1.y, a1.z + b1.z, a1.w + b1.w};
  float s = 0.f, sq = 0.f;
#pragma unroll
  for (int i = 0; i < 8; ++i) { s += x[i]; sq += x[i] * x[i]; }
#pragma unroll
  for (int off = 1; off < 64; off <<= 1) {
    s += __shfl_xor(s, off);
    sq += __shfl_xor(sq, off);
  }
  float mean = s * (1.f / 512.f);
  float var = sq * (1.f / 512.f) - mean * mean;
  float v = var + 1e-5f;
  float y = 0.5f;
#pragma unroll
  for (int it = 0; it < 3; ++it) y = y * (3.0f - v * y * y) * 0.5f;

  float4 g0 = ((const float4*)gamma)[lane];
  float4 g1 = ((const float4*)gamma)[lane + 64];
  float4 e0 = ((const float4*)beta)[lane];
  float4 e1 = ((const float4*)beta)[lane + 64];
  float o[8];
  o[0] = (x[0] - mean) * y * g0.x + e0.x;
  o[1] = (x[1] - mean) * y * g0.y + e0.y;
  o[2] = (x[2] - mean) * y * g0.z + e0.z;
  o[3] = (x[3] - mean) * y * g0.w + e0.w;
  o[4] = (x[4] - mean) * y * g1.x + e1.x;
  o[5] = (x[5] - mean) * y * g1.y + e1.y;
  o[6] = (x[6] - mean) * y * g1.z + e1.z;
  o[7] = (x[7] - mean) * y * g1.w + e1.w;
  float* po = outf + (size_t)row * 512;
  ((float4*)po)[lane]      = make_float4(o[0], o[1], o[2], o[3]);
  ((float4*)po)[lane + 64] = make_float4(o[4], o[5], o[6], o[7]);
  if (outb) {
    bf16_t* pq = outb + (size_t)row * 512;
    union { bf16_t h[4]; uint2 u; } c0, c1;
    c0.h[0] = (bf16_t)o[0]; c0.h[1] = (bf16_t)o[1]; c0.h[2] = (bf16_t)o[2]; c0.h[3] = (bf16_t)o[3];
    c1.h[0] = (bf16_t)o[4]; c1.h[1] = (bf16_t)o[5]; c1.h[2] = (bf16_t)o[6]; c1.h[3] = (bf16_t)o[7];
    ((uint2*)pq)[lane]      = c0.u;
    ((uint2*)pq)[lane + 64] = c1.u;
  }
}

// ---------------------------------------------------------------------------
extern "C" void kernel_launch(void* const* d_in, const int* in_sizes, int n_in,
                              void* d_out, int out_size, void* d_ws, size_t ws_size,
                              hipStream_t stream) {
  const float* x      = (const float*)d_in[0];
  const float* Wq     = (const float*)d_in[1];
  const float* Wk     = (const float*)d_in[2];
  const float* Wv     = (const float*)d_in[3];
  const float* Wo     = (const float*)d_in[4];
  const float* W1     = (const float*)d_in[5];
  const float* W2     = (const float*)d_in[6];
  const float* g1     = (const float*)d_in[7];
  const float* b1     = (const float*)d_in[8];
  const float* g2     = (const float*)d_in[9];
  const float* b2     = (const float*)d_in[10];
  const float* gelu_c = (const float*)d_in[11];
  const float* exp_c  = (const float*)d_in[12];

  const int M = 8192;  // B*T
  const size_t actBF = (size_t)M * 512 * 2;
  char* p = (char*)d_ws;
  auto carve = [&](size_t bytes) {
    void* r = (void*)p;
    p += (bytes + 255) & ~(size_t)255;
    return r;
  };
  bf16_t* x_bf   = (bf16_t*)carve(actBF);
  bf16_t* q_bf   = (bf16_t*)carve(actBF);
  bf16_t* k_bf   = (bf16_t*)carve(actBF);
  bf16_t* vT_bf  = (bf16_t*)carve(actBF);
  bf16_t* o_bf   = (bf16_t*)carve(actBF);
  bf16_t* h_bf   = (bf16_t*)carve(actBF);
  bf16_t* WqkvT  = (bf16_t*)carve((size_t)1536 * 512 * 2);
  bf16_t* WoT    = (bf16_t*)carve(512 * 512 * 2);
  bf16_t* W1T    = (bf16_t*)carve(512 * 2048 * 2);
  bf16_t* W2T    = (bf16_t*)carve(512 * 2048 * 2);
  bf16_t* g_bf   = (bf16_t*)carve((size_t)M * 2048 * 2);
  float*  proj   = (float*)carve((size_t)M * 512 * 4);
  float*  h_f    = (float*)carve((size_t)M * 512 * 4);
  float*  f2     = proj;  // proj dead after LN1; FFN2 output aliases it

  // prep
  k_cvt_bf16<<<4096, 256, 0, stream>>>(x, x_bf, M * 512 / 4);
  k_transpose_bf16<<<dim3(8, 8), 256, 0, stream>>>(Wq, WqkvT, 512, 512);
  k_transpose_bf16<<<dim3(8, 8), 256, 0, stream>>>(Wk, WqkvT + (size_t)512 * 512, 512, 512);
  k_transpose_bf16<<<dim3(8, 8), 256, 0, stream>>>(Wv, WqkvT + (size_t)1024 * 512, 512, 512);
  k_transpose_bf16<<<dim3(8, 8), 256, 0, stream>>>(Wo, WoT, 512, 512);
  k_transpose_bf16<<<dim3(8, 32), 256, 0, stream>>>(W1, W1T, 512, 2048);
  k_transpose_bf16<<<dim3(32, 8), 256, 0, stream>>>(W2, W2T, 2048, 512);

  // fused QKV projection
  k_gemm_bt<5, 128><<<dim3(64, 12), 256, 0, stream>>>(
      x_bf, WqkvT, nullptr, q_bf, k_bf, vT_bf, M, 1536, 512, nullptr);

  // attention (QBLK=64 -> 1024 blocks)
  k_attn<<<1024, 256, 0, stream>>>(q_bf, k_bf, vT_bf, o_bf, exp_c);

  // output projection
  k_gemm_bt<0, 64><<<dim3(128, 4), 256, 0, stream>>>(
      o_bf, WoT, proj, nullptr, nullptr, nullptr, M, 512, 512, nullptr);

  // LN1
  k_ln<<<2048, 256, 0, stream>>>(x, proj, g1, b1, h_f, h_bf);

  // FFN1: gelu(h @ W1) -> bf16
  k_gemm_bt<4, 128><<<dim3(64, 16), 256, 0, stream>>>(
      h_bf, W1T, nullptr, g_bf, nullptr, nullptr, M, 2048, 512, gelu_c);

  // FFN2
  k_gemm_bt<0, 64><<<dim3(128, 4), 256, 0, stream>>>(
      g_bf, W2T, f2, nullptr, nullptr, nullptr, M, 512, 2048, nullptr);

  // LN2
  k_ln<<<2048, 256, 0, stream>>>(h_f, f2, g2, b2, (float*)d_out, nullptr);
}

// Round 7
// 238.534 us; speedup vs baseline: 1.1340x; 1.1340x over previous
//
#include <hip/hip_runtime.h>
#include <hip/hip_bf16.h>

typedef __bf16 bf16_t;
typedef __bf16 bf16x8 __attribute__((ext_vector_type(8)));
typedef float f32x4 __attribute__((ext_vector_type(4)));

#define MFMA16(a, b, c) __builtin_amdgcn_mfma_f32_16x16x32_bf16((a), (b), (c), 0, 0, 0)

__device__ __forceinline__ void gl_lds16(const bf16_t* g, bf16_t* l) {
  __builtin_amdgcn_global_load_lds(
      (const __attribute__((address_space(1))) void*)g,
      (__attribute__((address_space(3))) void*)l, 16, 0, 0);
}

__device__ __forceinline__ unsigned pack_bf16(float a, float b) {
  union { bf16_t h[2]; unsigned u; } c;
  c.h[0] = (bf16_t)a; c.h[1] = (bf16_t)b;
  return c.u;
}

// B=4, T=2048, D=512, H=8, DH=64 — hardcoded
// ---------------------------------------------------------------------------
__global__ __launch_bounds__(256) void k_cvt_bf16(const float* __restrict__ in,
                                                  bf16_t* __restrict__ out, int n4) {
  int i = blockIdx.x * 256 + threadIdx.x;
  if (i >= n4) return;
  float4 f = ((const float4*)in)[i];
  union { bf16_t h[4]; uint2 u; } cv;
  cv.h[0] = (bf16_t)f.x; cv.h[1] = (bf16_t)f.y; cv.h[2] = (bf16_t)f.z; cv.h[3] = (bf16_t)f.w;
  ((uint2*)out)[i] = cv.u;
}

__global__ __launch_bounds__(256) void k_transpose_bf16(const float* __restrict__ W,
                                                        bf16_t* __restrict__ WT,
                                                        int K, int N) {
  __shared__ float tile[64][65];
  int bk = blockIdx.x * 64, bn = blockIdx.y * 64;
  int tx = threadIdx.x & 63, ty = threadIdx.x >> 6;
  for (int i = ty; i < 64; i += 4)
    tile[i][tx] = W[(size_t)(bk + i) * N + bn + tx];
  __syncthreads();
  for (int i = ty; i < 64; i += 4)
    WT[(size_t)(bn + i) * K + bk + tx] = (bf16_t)tile[tx][i];
}

// ---------------------------------------------------------------------------
// C[M][N] = A[M][K] @ Bt[N][K]^T, bf16 in, fp32 accum. 2-phase double-buffered
// global_load_lds staging.
// MODE 0: fp32 C    4: GELU poly -> bf16 C    5: fused QKV scatter where
//   K is stored pre-XOR-swizzled (d' = d ^ ((t&7)<<3)) and V is stored in the
//   gl_lds-linear permuted layout the attention kernel's PV step reads.
template <int MODE, int BM>
__global__ __launch_bounds__(256) void k_gemm_bt(
    const bf16_t* __restrict__ A, const bf16_t* __restrict__ Bt,
    float* __restrict__ Cf, bf16_t* __restrict__ Cb,
    bf16_t* __restrict__ Cb2, bf16_t* __restrict__ Cb3,
    int M, int N, int K, const float* __restrict__ coef) {
  __shared__ __align__(16) bf16_t As[2][BM * 32];
  __shared__ __align__(16) bf16_t Bs[2][128 * 32];
  constexpr int NF = (BM == 128) ? 4 : 2;
  int tid = threadIdx.x;
  int lane = tid & 63, wave = tid >> 6;
  int bm = blockIdx.x * BM, bn = blockIdx.y * 128;
  int wr = (BM == 128) ? (wave >> 1) * 64 : 0;
  int wc = (BM == 128) ? (wave & 1) * 64 : wave * 32;
  int lr = lane & 15, lk = (lane >> 4) * 8;
  int srow = tid >> 2, scol = (tid & 3) * 8;

  f32x4 zero = {0.f, 0.f, 0.f, 0.f};
  f32x4 acc[4][NF];
#pragma unroll
  for (int m = 0; m < 4; ++m)
#pragma unroll
    for (int n = 0; n < NF; ++n) acc[m][n] = zero;

  const bf16_t* pA = A + (size_t)(bm + srow) * K + scol;
  const bf16_t* pB = Bt + (size_t)(bn + srow) * K + scol;

  auto STAGE = [&](int buf, int k0) {
    bf16_t* lA = &As[buf][tid * 8];
    bf16_t* lB = &Bs[buf][tid * 8];
    gl_lds16(pA + k0, lA);
    if (BM == 128) gl_lds16(pA + (size_t)64 * K + k0, lA + 2048);
    gl_lds16(pB + k0, lB);
    gl_lds16(pB + (size_t)64 * K + k0, lB + 2048);
  };

  STAGE(0, 0);
  __syncthreads();
  int buf = 0;
  for (int k0 = 0; k0 < K; k0 += 32) {
    if (k0 + 32 < K) STAGE(buf ^ 1, k0 + 32);
    bf16x8 a[4], b[NF];
#pragma unroll
    for (int m = 0; m < 4; ++m) a[m] = *(const bf16x8*)&As[buf][(wr + m * 16 + lr) * 32 + lk];
#pragma unroll
    for (int n = 0; n < NF; ++n) b[n] = *(const bf16x8*)&Bs[buf][(wc + n * 16 + lr) * 32 + lk];
    __builtin_amdgcn_s_setprio(1);
#pragma unroll
    for (int m = 0; m < 4; ++m)
#pragma unroll
      for (int n = 0; n < NF; ++n)
        acc[m][n] = MFMA16(a[m], b[n], acc[m][n]);
    __builtin_amdgcn_s_setprio(0);
    __syncthreads();
    buf ^= 1;
  }

  float c8[8];
  if (MODE == 4) {
#pragma unroll
    for (int i = 0; i < 8; ++i) c8[i] = coef[i];
  }
  int rbase = (lane >> 4) * 4;
#pragma unroll
  for (int m = 0; m < 4; ++m) {
#pragma unroll
    for (int n = 0; n < NF; ++n) {
#pragma unroll
      for (int r = 0; r < 4; ++r) {
        int gm = bm + wr + m * 16 + rbase + r;
        int gn = bn + wc + n * 16 + lr;
        float v = acc[m][n][r];
        if (MODE == 0) {
          Cf[(size_t)gm * N + gn] = v;
        } else if (MODE == 4) {
          float xx = fminf(fmaxf(v, -4.f), 4.f);
          float p = c8[0], pw = 1.f;
#pragma unroll
          for (int i = 1; i < 8; ++i) { pw *= xx; p += c8[i] * pw; }
          Cb[(size_t)gm * N + gn] = (bf16_t)p;
        } else {  // 5: fused QKV scatter with attention-ready layouts
          int mat = gn >> 9, col = gn & 511;
          int b_ = gm >> 11, t_ = gm & 2047, h_ = col >> 6, d_ = col & 63;
          if (mat == 0) {
            Cb[(((size_t)b_ * 8 + h_) * 2048 + t_) * 64 + d_] = (bf16_t)v;
          } else if (mat == 1) {
            // K: pre-XOR-swizzle within each 128B row (read side applies same XOR)
            int dsw = d_ ^ ((t_ & 7) << 3);
            Cb2[(((size_t)b_ * 8 + h_) * 2048 + t_) * 64 + dsw] = (bf16_t)v;
          } else {
            // V: [dh][t] with PV quad-permutation + XOR swizzle baked in, so the
            // attention kernel stages each 64-wide tile as a linear byte stream.
            int tw = t_ & 63;
            int j = (((tw >> 2) & 3) << 1) | ((tw >> 4) & 1);
            int phys = (((tw & 32) << 1) + (j << 3) + ((tw & 3) << 1)) ^ ((d_ & 7) << 4);
            size_t e = ((((size_t)b_ * 8 + h_) * 64 + d_) * 4096 +
                        (size_t)(t_ >> 6) * 128 + phys) >> 1;
            Cb3[e] = (bf16_t)v;
          }
        }
      }
    }
  }
}

// ---------------------------------------------------------------------------
// Two-pass attention, QBLK=64, KVBLK=64, 4 waves (wave owns 16 q rows).
// Swapped QK^T (S^T = mfma(K,Q)), in-register scalar softmax (4 indep Horner
// chains), P packed straight into bf16 A-fragments. K/V staged by pure
// global_load_lds from pre-swizzled global layouts (linear LDS dest, swizzle
// applied on the LDS read). 2-phase double buffer, ONE barrier per kt.
__global__ __launch_bounds__(256) void k_attn(
    const bf16_t* __restrict__ qb, const bf16_t* __restrict__ kb,
    const bf16_t* __restrict__ vtb, bf16_t* __restrict__ ob,
    const float* __restrict__ exp_c) {
  __shared__ __align__(16) bf16_t Ks[2][64 * 64];
  __shared__ __align__(16) bf16_t Vs[2][64 * 64];
  int tid = threadIdx.x, lane = tid & 63, wave = tid >> 6;
  int b0 = blockIdx.x;
  int bid = (b0 & 7) * 128 + (b0 >> 3);  // XCD-chunked (1024 % 8 == 0)
  int qt = bid & 31, bh = bid >> 5;
  const size_t bho = (size_t)bh * (2048 * 64);
  const bf16_t* Q = qb + bho + (size_t)qt * 64 * 64;
  const bf16_t* Kp = kb + bho;   // rows pre-XOR-swizzled
  const bf16_t* Vp = vtb + bho;  // gl_lds-linear permuted [64 dh][2048 t]
  int lr = lane & 15, lg = lane >> 4;

  // Q fragments (registers, whole kernel). Q is B-operand: rows = q.
  bf16x8 qa[2];
#pragma unroll
  for (int h = 0; h < 2; ++h)
    qa[h] = *(const bf16x8*)&Q[(wave * 16 + lr) * 64 + h * 32 + lg * 8];

  float ec[7];
#pragma unroll
  for (int i = 0; i < 7; ++i) ec[i] = exp_c[i];

  // DMA staging: thread covers LDS bytes [tid*16, +16) and [4096+tid*16, +16)
  auto STAGE_K = [&](int buf, int kt) {
    bf16_t* lk = &Ks[buf][tid * 8];
    const bf16_t* gk = Kp + (size_t)kt * 4096 + tid * 8;
    gl_lds16(gk, lk);
    gl_lds16(gk + 2048, lk + 2048);
  };
  auto STAGE_V = [&](int buf, int kt) {
    bf16_t* lv = &Vs[buf][tid * 8];
    const bf16_t* gv = Vp + (size_t)(tid >> 3) * 2048 + kt * 64 + (tid & 7) * 8;
    gl_lds16(gv, lv);
    gl_lds16(gv + (size_t)32 * 2048, lv + 2048);
  };

  f32x4 zero = {0.f, 0.f, 0.f, 0.f};

  // ================= pass 1: exact row max (S^T layout) =================
  STAGE_K(0, 0);
  __syncthreads();
  float rmax = -3.4e38f;
  int cur = 0;
  for (int kt = 0; kt < 32; ++kt) {
    if (kt < 31) STAGE_K(cur ^ 1, kt + 1);
    const char* kbase = (const char*)Ks[cur];
    __builtin_amdgcn_s_setprio(1);
#pragma unroll
    for (int n = 0; n < 4; ++n) {
      int row = n * 16 + lr, sw = (row & 7) << 4;
      bf16x8 kb0 = *(const bf16x8*)(kbase + ((row * 128 + lg * 16) ^ sw));
      bf16x8 kb1 = *(const bf16x8*)(kbase + ((row * 128 + 64 + lg * 16) ^ sw));
      f32x4 s = MFMA16(kb1, qa[1], MFMA16(kb0, qa[0], zero));
#pragma unroll
      for (int r = 0; r < 4; ++r) rmax = fmaxf(rmax, s[r]);
    }
    __builtin_amdgcn_s_setprio(0);
    __syncthreads();
    cur ^= 1;
  }
  rmax = fmaxf(rmax, __shfl_xor(rmax, 16));
  rmax = fmaxf(rmax, __shfl_xor(rmax, 32));
  float rm8 = rmax * 0.125f;  // exact (pow2)

  // ================= pass 2 =================
  f32x4 oacc[4];
#pragma unroll
  for (int n = 0; n < 4; ++n) oacc[n] = zero;
  float rsum = 0.f;

  STAGE_K(0, 0);
  STAGE_V(0, 0);
  __syncthreads();

  cur = 0;
  for (int kt = 0; kt < 32; ++kt) {
    if (kt < 31) {
      STAGE_K(cur ^ 1, kt + 1);
      STAGE_V(cur ^ 1, kt + 1);
    }
    const char* kbase = (const char*)Ks[cur];
    const char* vbase = (const char*)Vs[cur];
    // ---- QK^T (swapped) + poly + pack to bf16 A-fragments (in-register)
    unsigned pk[4][2];
    __builtin_amdgcn_s_setprio(1);
#pragma unroll
    for (int n = 0; n < 4; ++n) {
      int row = n * 16 + lr, sw = (row & 7) << 4;
      bf16x8 kb0 = *(const bf16x8*)(kbase + ((row * 128 + lg * 16) ^ sw));
      bf16x8 kb1 = *(const bf16x8*)(kbase + ((row * 128 + 64 + lg * 16) ^ sw));
      f32x4 s = MFMA16(kb1, qa[1], MFMA16(kb0, qa[0], zero));
      float pf[4];
#pragma unroll
      for (int r = 0; r < 4; ++r) {
        float x = __builtin_fmaf(s[r], 0.125f, -rm8);  // == (s-rmax)/8 exactly
        float p = ec[6];
#pragma unroll
        for (int i = 5; i >= 0; --i) p = __builtin_fmaf(p, x, ec[i]);
        p = fmaxf(p, 1e-8f);
        rsum += p;
        pf[r] = p;
      }
      pk[n][0] = pack_bf16(pf[0], pf[1]);
      pk[n][1] = pack_bf16(pf[2], pf[3]);
    }
    __builtin_amdgcn_s_setprio(0);
    union { unsigned u[4]; bf16x8 v; } pa0, pa1;
    pa0.u[0] = pk[0][0]; pa0.u[1] = pk[0][1]; pa0.u[2] = pk[1][0]; pa0.u[3] = pk[1][1];
    pa1.u[0] = pk[2][0]; pa1.u[1] = pk[2][1]; pa1.u[2] = pk[3][0]; pa1.u[3] = pk[3][1];
    // ---- PV: oacc[dd] += P(k-chunk) x V(perm-staged)
    __builtin_amdgcn_s_setprio(1);
#pragma unroll
    for (int dd = 0; dd < 4; ++dd) {
      int row = dd * 16 + lr, sw = (row & 7) << 4;
      bf16x8 v0 = *(const bf16x8*)(vbase + ((row * 128 + lg * 16) ^ sw));
      bf16x8 v1 = *(const bf16x8*)(vbase + ((row * 128 + 64 + lg * 16) ^ sw));
      oacc[dd] = MFMA16(pa1.v, v1, MFMA16(pa0.v, v0, oacc[dd]));
    }
    __builtin_amdgcn_s_setprio(0);
    __syncthreads();
    cur ^= 1;
  }
  rsum += __shfl_xor(rsum, 16);
  rsum += __shfl_xor(rsum, 32);
  float rs4[4];
#pragma unroll
  for (int r = 0; r < 4; ++r) rs4[r] = __shfl(rsum, lg * 4 + r);

  int b_ = bh >> 3, h_ = bh & 7;
#pragma unroll
  for (int dd = 0; dd < 4; ++dd)
#pragma unroll
    for (int r = 0; r < 4; ++r) {
      int t_ = qt * 64 + wave * 16 + lg * 4 + r;
      int d_ = dd * 16 + lr;
      float val = oacc[dd][r] / rs4[r];
      ob[(((size_t)b_ * 2048 + t_) * 8 + h_) * 64 + d_] = (bf16_t)val;
    }
}

// ---------------------------------------------------------------------------
// Fused residual + LayerNorm (replicates Newton rsqrt exactly: 3 iters from 0.5).
__global__ __launch_bounds__(256) void k_ln(
    const float* __restrict__ xa, const float* __restrict__ xb,
    const float* __restrict__ gamma, const float* __restrict__ beta,
    float* __restrict__ outf, bf16_t* __restrict__ outb) {
  int row = blockIdx.x * 4 + (threadIdx.x >> 6);
  int lane = threadIdx.x & 63;
  const float* pa = xa + (size_t)row * 512;
  const float* pb = xb + (size_t)row * 512;
  float4 a0 = ((const float4*)pa)[lane];
  float4 a1 = ((const float4*)pa)[lane + 64];
  float4 b0 = ((const float4*)pb)[lane];
  float4 b1 = ((const float4*)pb)[lane + 64];
  float x[8] = {a0.x + b0.x, a0.y + b0.y, a0.z + b0.z, a0.w + b0.w,
                a1.x + b1.x, a1.y + b1.y, a1.z + b1.z, a1.w + b1.w};
  float s = 0.f, sq = 0.f;
#pragma unroll
  for (int i = 0; i < 8; ++i) { s += x[i]; sq += x[i] * x[i]; }
#pragma unroll
  for (int off = 1; off < 64; off <<= 1) {
    s += __shfl_xor(s, off);
    sq += __shfl_xor(sq, off);
  }
  float mean = s * (1.f / 512.f);
  float var = sq * (1.f / 512.f) - mean * mean;
  float v = var + 1e-5f;
  float y = 0.5f;
#pragma unroll
  for (int it = 0; it < 3; ++it) y = y * (3.0f - v * y * y) * 0.5f;

  float4 g0 = ((const float4*)gamma)[lane];
  float4 g1 = ((const float4*)gamma)[lane + 64];
  float4 e0 = ((const float4*)beta)[lane];
  float4 e1 = ((const float4*)beta)[lane + 64];
  float o[8];
  o[0] = (x[0] - mean) * y * g0.x + e0.x;
  o[1] = (x[1] - mean) * y * g0.y + e0.y;
  o[2] = (x[2] - mean) * y * g0.z + e0.z;
  o[3] = (x[3] - mean) * y * g0.w + e0.w;
  o[4] = (x[4] - mean) * y * g1.x + e1.x;
  o[5] = (x[5] - mean) * y * g1.y + e1.y;
  o[6] = (x[6] - mean) * y * g1.z + e1.z;
  o[7] = (x[7] - mean) * y * g1.w + e1.w;
  float* po = outf + (size_t)row * 512;
  ((float4*)po)[lane]      = make_float4(o[0], o[1], o[2], o[3]);
  ((float4*)po)[lane + 64] = make_float4(o[4], o[5], o[6], o[7]);
  if (outb) {
    bf16_t* pq = outb + (size_t)row * 512;
    union { bf16_t h[4]; uint2 u; } c0, c1;
    c0.h[0] = (bf16_t)o[0]; c0.h[1] = (bf16_t)o[1]; c0.h[2] = (bf16_t)o[2]; c0.h[3] = (bf16_t)o[3];
    c1.h[0] = (bf16_t)o[4]; c1.h[1] = (bf16_t)o[5]; c1.h[2] = (bf16_t)o[6]; c1.h[3] = (bf16_t)o[7];
    ((uint2*)pq)[lane]      = c0.u;
    ((uint2*)pq)[lane + 64] = c1.u;
  }
}

// ---------------------------------------------------------------------------
extern "C" void kernel_launch(void* const* d_in, const int* in_sizes, int n_in,
                              void* d_out, int out_size, void* d_ws, size_t ws_size,
                              hipStream_t stream) {
  const float* x      = (const float*)d_in[0];
  const float* Wq     = (const float*)d_in[1];
  const float* Wk     = (const float*)d_in[2];
  const float* Wv     = (const float*)d_in[3];
  const float* Wo     = (const float*)d_in[4];
  const float* W1     = (const float*)d_in[5];
  const float* W2     = (const float*)d_in[6];
  const float* g1     = (const float*)d_in[7];
  const float* b1     = (const float*)d_in[8];
  const float* g2     = (const float*)d_in[9];
  const float* b2     = (const float*)d_in[10];
  const float* gelu_c = (const float*)d_in[11];
  const float* exp_c  = (const float*)d_in[12];

  const int M = 8192;  // B*T
  const size_t actBF = (size_t)M * 512 * 2;
  char* p = (char*)d_ws;
  auto carve = [&](size_t bytes) {
    void* r = (void*)p;
    p += (bytes + 255) & ~(size_t)255;
    return r;
  };
  bf16_t* x_bf   = (bf16_t*)carve(actBF);
  bf16_t* q_bf   = (bf16_t*)carve(actBF);
  bf16_t* k_bf   = (bf16_t*)carve(actBF);
  bf16_t* vT_bf  = (bf16_t*)carve(actBF);
  bf16_t* o_bf   = (bf16_t*)carve(actBF);
  bf16_t* h_bf   = (bf16_t*)carve(actBF);
  bf16_t* WqkvT  = (bf16_t*)carve((size_t)1536 * 512 * 2);
  bf16_t* WoT    = (bf16_t*)carve(512 * 512 * 2);
  bf16_t* W1T    = (bf16_t*)carve(512 * 2048 * 2);
  bf16_t* W2T    = (bf16_t*)carve(512 * 2048 * 2);
  bf16_t* g_bf   = (bf16_t*)carve((size_t)M * 2048 * 2);
  float*  proj   = (float*)carve((size_t)M * 512 * 4);
  float*  h_f    = (float*)carve((size_t)M * 512 * 4);
  float*  f2     = proj;  // proj dead after LN1; FFN2 output aliases it

  // prep
  k_cvt_bf16<<<4096, 256, 0, stream>>>(x, x_bf, M * 512 / 4);
  k_transpose_bf16<<<dim3(8, 8), 256, 0, stream>>>(Wq, WqkvT, 512, 512);
  k_transpose_bf16<<<dim3(8, 8), 256, 0, stream>>>(Wk, WqkvT + (size_t)512 * 512, 512, 512);
  k_transpose_bf16<<<dim3(8, 8), 256, 0, stream>>>(Wv, WqkvT + (size_t)1024 * 512, 512, 512);
  k_transpose_bf16<<<dim3(8, 8), 256, 0, stream>>>(Wo, WoT, 512, 512);
  k_transpose_bf16<<<dim3(8, 32), 256, 0, stream>>>(W1, W1T, 512, 2048);
  k_transpose_bf16<<<dim3(32, 8), 256, 0, stream>>>(W2, W2T, 2048, 512);

  // fused QKV projection (K/V written in attention-ready layouts)
  k_gemm_bt<5, 128><<<dim3(64, 12), 256, 0, stream>>>(
      x_bf, WqkvT, nullptr, q_bf, k_bf, vT_bf, M, 1536, 512, nullptr);

  // attention (QBLK=64 -> 1024 blocks)
  k_attn<<<1024, 256, 0, stream>>>(q_bf, k_bf, vT_bf, o_bf, exp_c);

  // output projection
  k_gemm_bt<0, 64><<<dim3(128, 4), 256, 0, stream>>>(
      o_bf, WoT, proj, nullptr, nullptr, nullptr, M, 512, 512, nullptr);

  // LN1
  k_ln<<<2048, 256, 0, stream>>>(x, proj, g1, b1, h_f, h_bf);

  // FFN1: gelu(h @ W1) -> bf16
  k_gemm_bt<4, 128><<<dim3(64, 16), 256, 0, stream>>>(
      h_bf, W1T, nullptr, g_bf, nullptr, nullptr, M, 2048, 512, gelu_c);

  // FFN2
  k_gemm_bt<0, 64><<<dim3(128, 4), 256, 0, stream>>>(
      g_bf, W2T, f2, nullptr, nullptr, nullptr, M, 512, 2048, nullptr);

  // LN2
  k_ln<<<2048, 256, 0, stream>>>(h_f, f2, g2, b2, (float*)d_out, nullptr);
}